// Round 1
// baseline (2001.168 us; speedup 1.0000x reference)
//
#include <hip/hip_runtime.h>

#define NE   8
#define TPE  1024
#define HID  2048
#define EXD  4096
#define FF   8192  // 2*EXD

typedef short short8 __attribute__((ext_vector_type(8)));
typedef float f32x4 __attribute__((ext_vector_type(4)));

// fp32 -> bf16 (RNE), two packed into one uint (low = a, high = b)
__device__ __forceinline__ unsigned int pk2bf(float a, float b) {
  unsigned int ua = __float_as_uint(a);
  unsigned int ub = __float_as_uint(b);
  ua = (ua + 0x7fffu + ((ua >> 16) & 1u)) >> 16;
  ub = (ub + 0x7fffu + ((ub >> 16) & 1u)) >> 16;
  return ua | (ub << 16);
}

__device__ __forceinline__ unsigned short f2bf(float a) {
  unsigned int ua = __float_as_uint(a);
  return (unsigned short)((ua + 0x7fffu + ((ua >> 16) & 1u)) >> 16);
}

// GEMM1 fused with silu-gating:
//   gated[e,t,i] = up * silu(gate),  gate_up = x_e @ W1_e
// Tiles: BM=128, BN=128 (gated cols), BK=32. 256 threads = 4 waves (2x2).
// LDS layout is TN: As[m][k], Bg/Bu[n][k] (k contiguous, bf16) so fragment
// reads are single ds_read_b128 per operand per MFMA tile.
__global__ __launch_bounds__(256) void gemm1_silu(
    const float* __restrict__ x, const float* __restrict__ w1,
    unsigned short* __restrict__ gated) {
  __shared__ unsigned short As[128 * 32];
  __shared__ unsigned short Bg[128 * 32];
  __shared__ unsigned short Bu[128 * 32];

  const int e  = blockIdx.z;
  const int t0 = blockIdx.y * 128;
  const int i0 = blockIdx.x * 128;
  const int t  = threadIdx.x;
  const int lane = t & 63, wv = t >> 6, wm = wv & 1, wn = wv >> 1;

  const float* xA  = x  + (size_t)(e * TPE + t0) * HID;
  const float* w1e = w1 + (size_t)e * HID * FF;

  const int mA = t >> 1, hA = t & 1;    // A staging: thread -> (row, 16k-half)
  const int nB = t & 127, gB = t >> 7;  // B staging: thread -> (n col, k octet group)

  f32x4 accg[4][4], accu[4][4];
  const f32x4 vzero = {0.f, 0.f, 0.f, 0.f};
  #pragma unroll
  for (int a = 0; a < 4; ++a)
    #pragma unroll
    for (int b = 0; b < 4; ++b) { accg[a][b] = vzero; accu[a][b] = vzero; }

  for (int k0 = 0; k0 < HID; k0 += 32) {
    // ---- stage A: x is k-contiguous in global; float4 loads + pack ----
    {
      const float* ap = xA + (size_t)mA * HID + k0 + hA * 16;
      float4 a0 = *(const float4*)(ap + 0);
      float4 a1 = *(const float4*)(ap + 4);
      float4 a2 = *(const float4*)(ap + 8);
      float4 a3 = *(const float4*)(ap + 12);
      uint4 p0, p1;
      p0.x = pk2bf(a0.x, a0.y); p0.y = pk2bf(a0.z, a0.w);
      p0.z = pk2bf(a1.x, a1.y); p0.w = pk2bf(a1.z, a1.w);
      p1.x = pk2bf(a2.x, a2.y); p1.y = pk2bf(a2.z, a2.w);
      p1.z = pk2bf(a3.x, a3.y); p1.w = pk2bf(a3.z, a3.w);
      *(uint4*)&As[mA * 32 + hA * 16 + 0] = p0;
      *(uint4*)&As[mA * 32 + hA * 16 + 8] = p1;
    }
    // ---- stage Bg/Bu: W1 is n-contiguous; gather 8 k-rows per thread,
    //      write one b128 (8 bf16, contiguous k) per tile -> transpose ----
    #pragma unroll
    for (int it = 0; it < 2; ++it) {
      const int kb = gB * 8 + it * 16;
      const float* bp = w1e + (size_t)(k0 + kb) * FF + i0 + nB;
      float gv[8], uv[8];
      #pragma unroll
      for (int r = 0; r < 8; ++r) {
        gv[r] = bp[(size_t)r * FF];
        uv[r] = bp[(size_t)r * FF + EXD];
      }
      uint4 pg, pu;
      pg.x = pk2bf(gv[0], gv[1]); pg.y = pk2bf(gv[2], gv[3]);
      pg.z = pk2bf(gv[4], gv[5]); pg.w = pk2bf(gv[6], gv[7]);
      pu.x = pk2bf(uv[0], uv[1]); pu.y = pk2bf(uv[2], uv[3]);
      pu.z = pk2bf(uv[4], uv[5]); pu.w = pk2bf(uv[6], uv[7]);
      *(uint4*)&Bg[nB * 32 + kb] = pg;
      *(uint4*)&Bu[nB * 32 + kb] = pu;
    }
    __syncthreads();

    // ---- compute: one k-step (K=32) of 4x4 MFMA tiles, dual acc ----
    short8 af[4], bgf[4], buf2[4];
    #pragma unroll
    for (int mi = 0; mi < 4; ++mi)
      af[mi] = *(const short8*)&As[(wm * 64 + mi * 16 + (lane & 15)) * 32 + (lane >> 4) * 8];
    #pragma unroll
    for (int ni = 0; ni < 4; ++ni) {
      const int ro = (wn * 64 + ni * 16 + (lane & 15)) * 32 + (lane >> 4) * 8;
      bgf[ni] = *(const short8*)&Bg[ro];
      buf2[ni] = *(const short8*)&Bu[ro];
    }
    #pragma unroll
    for (int mi = 0; mi < 4; ++mi)
      #pragma unroll
      for (int ni = 0; ni < 4; ++ni) {
        accg[mi][ni] = __builtin_amdgcn_mfma_f32_16x16x32_bf16(af[mi], bgf[ni], accg[mi][ni], 0, 0, 0);
        accu[mi][ni] = __builtin_amdgcn_mfma_f32_16x16x32_bf16(af[mi], buf2[ni], accu[mi][ni], 0, 0, 0);
      }
    __syncthreads();
  }

  // ---- epilogue: silu-gate, bf16 store to workspace ----
  // C/D layout (m89-verified): col = lane&15, row = (lane>>4)*4 + reg
  const int r0 = t0 + wm * 64;
  const int c0 = i0 + wn * 64;
  const int qr = (lane >> 4) * 4, cl = lane & 15;
  #pragma unroll
  for (int mi = 0; mi < 4; ++mi)
    #pragma unroll
    for (int ni = 0; ni < 4; ++ni)
      #pragma unroll
      for (int v = 0; v < 4; ++v) {
        const int r = r0 + mi * 16 + qr + v;
        const int c = c0 + ni * 16 + cl;
        const float g = accg[mi][ni][v];
        const float u = accu[mi][ni][v];
        const float s = g / (1.f + __expf(-g));  // silu; -g large -> exp=inf -> s=-0 (ok)
        gated[(size_t)(e * TPE + r) * EXD + c] = f2bf(u * s);
      }
}

// GEMM2: out[e,t,h] = gated[e,t,:] @ W2_e[:,h], fp32 out.
__global__ __launch_bounds__(256) void gemm2(
    const unsigned short* __restrict__ gated, const float* __restrict__ w2,
    float* __restrict__ out) {
  __shared__ unsigned short As[128 * 32];
  __shared__ unsigned short Bs[128 * 32];

  const int e  = blockIdx.z;
  const int t0 = blockIdx.y * 128;
  const int h0 = blockIdx.x * 128;
  const int t  = threadIdx.x;
  const int lane = t & 63, wv = t >> 6, wm = wv & 1, wn = wv >> 1;

  const unsigned short* Ae = gated + (size_t)(e * TPE + t0) * EXD;
  const float* w2e = w2 + (size_t)e * EXD * HID;

  const int arow = t >> 2, ac8 = (t & 3) * 8;  // A staging (bf16 straight copy)
  const int nB = t & 127, gB = t >> 7;         // B staging (convert-transpose)

  f32x4 acc[4][4];
  const f32x4 vzero = {0.f, 0.f, 0.f, 0.f};
  #pragma unroll
  for (int a = 0; a < 4; ++a)
    #pragma unroll
    for (int b = 0; b < 4; ++b) acc[a][b] = vzero;

  for (int k0 = 0; k0 < EXD; k0 += 32) {
    // ---- stage A: already bf16, k-contiguous: uint4 copy ----
    #pragma unroll
    for (int rr = 0; rr < 2; ++rr) {
      const unsigned short* gp = Ae + (size_t)(rr * 64 + arow) * EXD + k0 + ac8;
      *(uint4*)&As[rr * 2048 + t * 8] = *(const uint4*)gp;
    }
    // ---- stage B: W2 fp32 n-contiguous -> bf16 [n][k] ----
    #pragma unroll
    for (int it = 0; it < 2; ++it) {
      const int kb = gB * 8 + it * 16;
      const float* bp = w2e + (size_t)(k0 + kb) * HID + h0 + nB;
      float bv[8];
      #pragma unroll
      for (int r = 0; r < 8; ++r) bv[r] = bp[(size_t)r * HID];
      uint4 pb;
      pb.x = pk2bf(bv[0], bv[1]); pb.y = pk2bf(bv[2], bv[3]);
      pb.z = pk2bf(bv[4], bv[5]); pb.w = pk2bf(bv[6], bv[7]);
      *(uint4*)&Bs[nB * 32 + kb] = pb;
    }
    __syncthreads();

    short8 af[4], bfr[4];
    #pragma unroll
    for (int mi = 0; mi < 4; ++mi)
      af[mi] = *(const short8*)&As[(wm * 64 + mi * 16 + (lane & 15)) * 32 + (lane >> 4) * 8];
    #pragma unroll
    for (int ni = 0; ni < 4; ++ni)
      bfr[ni] = *(const short8*)&Bs[(wn * 64 + ni * 16 + (lane & 15)) * 32 + (lane >> 4) * 8];
    #pragma unroll
    for (int mi = 0; mi < 4; ++mi)
      #pragma unroll
      for (int ni = 0; ni < 4; ++ni)
        acc[mi][ni] = __builtin_amdgcn_mfma_f32_16x16x32_bf16(af[mi], bfr[ni], acc[mi][ni], 0, 0, 0);
    __syncthreads();
  }

  const int r0 = t0 + wm * 64;
  const int c0 = h0 + wn * 64;
  const int qr = (lane >> 4) * 4, cl = lane & 15;
  #pragma unroll
  for (int mi = 0; mi < 4; ++mi)
    #pragma unroll
    for (int ni = 0; ni < 4; ++ni)
      #pragma unroll
      for (int v = 0; v < 4; ++v) {
        const int r = r0 + mi * 16 + qr + v;
        const int c = c0 + ni * 16 + cl;
        out[(size_t)(e * TPE + r) * HID + c] = acc[mi][ni][v];
      }
}

extern "C" void kernel_launch(void* const* d_in, const int* in_sizes, int n_in,
                              void* d_out, int out_size, void* d_ws, size_t ws_size,
                              hipStream_t stream) {
  const float* x  = (const float*)d_in[0];   // [8192, 2048] fp32
  const float* w1 = (const float*)d_in[1];   // [8, 2048, 8192] fp32
  const float* w2 = (const float*)d_in[2];   // [8, 4096, 2048] fp32
  float* out = (float*)d_out;                // [8192, 2048] fp32
  unsigned short* gated = (unsigned short*)d_ws;  // [8, 1024, 4096] bf16 = 64 MiB

  dim3 blk(256, 1, 1);
  dim3 g1(EXD / 128, TPE / 128, NE);  // (32, 8, 8)
  dim3 g2(HID / 128, TPE / 128, NE);  // (16, 8, 8)
  gemm1_silu<<<g1, blk, 0, stream>>>(x, w1, gated);
  gemm2<<<g2, blk, 0, stream>>>(gated, w2, out);
}